// Round 2
// baseline (1158.048 us; speedup 1.0000x reference)
//
#include <hip/hip_runtime.h>
#include <hip/hip_bf16.h>
#include <stdint.h>

#define TOKENS 8192
#define DIM 2048
#define EXPERTS 64
#define CAP 256
#define COMB_ELEMS ((size_t)TOKENS * EXPERTS * CAP)  // 134217728

#ifndef GUMBEL_ORIGINAL
#define GUMBEL_ORIGINAL 0   // 0 = jax_threefry_partitionable (modern default)
#endif

// ---------------- threefry2x32 (exact JAX semantics) ----------------
__device__ __forceinline__ void tf_round(uint32_t& a, uint32_t& b, int r) {
  a += b;
  b = (b << r) | (b >> (32 - r));
  b ^= a;
}

__device__ __forceinline__ void threefry2x32(uint32_t k0, uint32_t k1,
                                             uint32_t x0, uint32_t x1,
                                             uint32_t& o0, uint32_t& o1) {
  const uint32_t ks0 = k0, ks1 = k1, ks2 = k0 ^ k1 ^ 0x1BD11BDAu;
  x0 += ks0; x1 += ks1;
  tf_round(x0, x1, 13); tf_round(x0, x1, 15); tf_round(x0, x1, 26); tf_round(x0, x1, 6);
  x0 += ks1; x1 += ks2 + 1u;
  tf_round(x0, x1, 17); tf_round(x0, x1, 29); tf_round(x0, x1, 16); tf_round(x0, x1, 24);
  x0 += ks2; x1 += ks0 + 2u;
  tf_round(x0, x1, 13); tf_round(x0, x1, 15); tf_round(x0, x1, 26); tf_round(x0, x1, 6);
  x0 += ks0; x1 += ks1 + 3u;
  tf_round(x0, x1, 17); tf_round(x0, x1, 29); tf_round(x0, x1, 16); tf_round(x0, x1, 24);
  x0 += ks1; x1 += ks2 + 4u;
  tf_round(x0, x1, 13); tf_round(x0, x1, 15); tf_round(x0, x1, 26); tf_round(x0, x1, 6);
  x0 += ks2; x1 += ks0 + 5u;
  o0 = x0; o1 = x1;
}

// ---------------- K1: logits = x @ wg^T  (fp32 vector GEMM) ----------------
// grid 256 blocks (32 tokens each), 256 threads; tile 32x64, BK=32.
__global__ __launch_bounds__(256) void k_logits(const float* __restrict__ x,
                                                const float* __restrict__ wg,
                                                float* __restrict__ logits) {
  __shared__ float xs[32][33];    // pad 33: conflict-free compute reads
  __shared__ float wsm[64][33];
  const int tid = threadIdx.x;
  const int tok0 = blockIdx.x * 32;
  const int tx = tid & 15;        // expert group (4 experts)
  const int ty = tid >> 4;        // token group (2 tokens)
  const int e0 = tx * 4;
  const int t0 = ty * 2;

  const int xr = tid >> 3;            // 0..31
  const int xc = (tid & 7) << 2;      // 0,4,..,28
  const int wr = tid >> 2;            // 0..63
  const int wc = (tid & 3) << 3;      // 0,8,16,24

  const float* xp = x + (size_t)(tok0 + xr) * DIM + xc;
  const float* wp = wg + (size_t)wr * DIM + wc;

  float4 xv  = *reinterpret_cast<const float4*>(xp);
  float4 wv0 = *reinterpret_cast<const float4*>(wp);
  float4 wv1 = *reinterpret_cast<const float4*>(wp + 4);

  float acc[2][4] = {{0.f, 0.f, 0.f, 0.f}, {0.f, 0.f, 0.f, 0.f}};

  for (int k0 = 0; k0 < DIM; k0 += 32) {
    xs[xr][xc] = xv.x; xs[xr][xc + 1] = xv.y; xs[xr][xc + 2] = xv.z; xs[xr][xc + 3] = xv.w;
    wsm[wr][wc]     = wv0.x; wsm[wr][wc + 1] = wv0.y; wsm[wr][wc + 2] = wv0.z; wsm[wr][wc + 3] = wv0.w;
    wsm[wr][wc + 4] = wv1.x; wsm[wr][wc + 5] = wv1.y; wsm[wr][wc + 6] = wv1.z; wsm[wr][wc + 7] = wv1.w;
    __syncthreads();
    if (k0 + 32 < DIM) {  // prefetch next tile into regs; overlaps compute
      xv  = *reinterpret_cast<const float4*>(xp + k0 + 32);
      wv0 = *reinterpret_cast<const float4*>(wp + k0 + 32);
      wv1 = *reinterpret_cast<const float4*>(wp + k0 + 36);
    }
#pragma unroll
    for (int kk = 0; kk < 32; ++kk) {
      const float a0 = xs[t0][kk];
      const float a1 = xs[t0 + 1][kk];
      const float b0 = wsm[e0][kk];
      const float b1 = wsm[e0 + 1][kk];
      const float b2 = wsm[e0 + 2][kk];
      const float b3 = wsm[e0 + 3][kk];
      acc[0][0] = fmaf(a0, b0, acc[0][0]);
      acc[0][1] = fmaf(a0, b1, acc[0][1]);
      acc[0][2] = fmaf(a0, b2, acc[0][2]);
      acc[0][3] = fmaf(a0, b3, acc[0][3]);
      acc[1][0] = fmaf(a1, b0, acc[1][0]);
      acc[1][1] = fmaf(a1, b1, acc[1][1]);
      acc[1][2] = fmaf(a1, b2, acc[1][2]);
      acc[1][3] = fmaf(a1, b3, acc[1][3]);
    }
    __syncthreads();
  }
#pragma unroll
  for (int i = 0; i < 2; ++i)
#pragma unroll
    for (int j = 0; j < 4; ++j)
      logits[(size_t)(tok0 + t0 + i) * EXPERTS + e0 + j] = acc[i][j];
}

// ---------------- K2: softmax + argmax1 + gumbel + argmax2 ----------------
// wave per token (lane == expert). grid 2048 x 256.
__global__ __launch_bounds__(256) void k_gate(const float* __restrict__ logits,
    float* __restrict__ gates, int* __restrict__ e1, int* __restrict__ e2,
    float* __restrict__ g1, float* __restrict__ g2) {
  const int lane = threadIdx.x & 63;
  const int t = blockIdx.x * 4 + (threadIdx.x >> 6);
  const float logit = logits[(size_t)t * EXPERTS + lane];

  // softmax over 64 experts
  float m = logit;
#pragma unroll
  for (int off = 32; off > 0; off >>= 1) m = fmaxf(m, __shfl_xor(m, off));
  const float ex = expf(logit - m);
  float s = ex;
#pragma unroll
  for (int off = 32; off > 0; off >>= 1) s += __shfl_xor(s, off);
  const float gate = ex / s;
  gates[(size_t)t * EXPERTS + lane] = gate;

  // argmax1 (first-index tie-break), on logits (softmax is monotonic)
  float v1 = logit; int i1 = lane;
#pragma unroll
  for (int off = 32; off > 0; off >>= 1) {
    const float ov = __shfl_xor(v1, off);
    const int oi = __shfl_xor(i1, off);
    if (ov > v1 || (ov == v1 && oi < i1)) { v1 = ov; i1 = oi; }
  }

  // gumbel(key=42) at flat index i = t*64+e, reproducing JAX bit-exactly
  const uint32_t i_flat = (uint32_t)t * 64u + (uint32_t)lane;
  uint32_t b0, b1, bits;
#if GUMBEL_ORIGINAL
  const uint32_t H = (TOKENS * EXPERTS) / 2;
  const uint32_t cj = i_flat < H ? i_flat : i_flat - H;
  threefry2x32(0u, 42u, cj, cj + H, b0, b1);
  bits = (i_flat < H) ? b0 : b1;
#else
  // partitionable path: counter = (hi=0, lo=i); 32-bit output = o0 ^ o1
  threefry2x32(0u, 42u, 0u, i_flat, b0, b1);
  bits = b0 ^ b1;
#endif
  float u = __uint_as_float((bits >> 9) | 0x3f800000u) - 1.0f;  // [0,1)
  // uniform(minval=tiny): u*(1-tiny)+tiny then max(tiny, .) == u + tiny in fp32
  u += 1.17549435e-38f;
  const float gum = -logf(-logf(u));
  const float noisy = (lane == i1) ? -__builtin_inff() : (logit + gum);

  float v2 = noisy; int i2 = lane;
#pragma unroll
  for (int off = 32; off > 0; off >>= 1) {
    const float ov = __shfl_xor(v2, off);
    const int oi = __shfl_xor(i2, off);
    if (ov > v2 || (ov == v2 && oi < i2)) { v2 = ov; i2 = oi; }
  }

  const float gate1 = __shfl(gate, i1);
  const float gate2 = __shfl(gate, i2);
  if (lane == 0) { e1[t] = i1; e2[t] = i2; g1[t] = gate1; g2[t] = gate2; }
}

// ---------------- K3: per-expert prefix ranks (cumsum) + counts + col-sum ----
// block per expert (64 blocks x 256 threads); ballot-scan in token order.
__global__ __launch_bounds__(256) void k_scan(const int* __restrict__ e1,
    const int* __restrict__ e2, const float* __restrict__ gates,
    int* __restrict__ loc1, int* __restrict__ loc2,
    int* __restrict__ counts1, float* __restrict__ gsum) {
  const int e = blockIdx.x;
  const int tid = threadIdx.x;
  const int lane = tid & 63;
  const int w = tid >> 6;
  __shared__ int wt[4];
  __shared__ int carry;
  __shared__ float gw[4];
  if (tid == 0) carry = 0;

  float gs = 0.f;
  // pass 1: ranks among top-1 pickers of expert e (+ gates column sum)
  for (int base = 0; base < TOKENS; base += 256) {
    const int t = base + tid;
    const int p = (e1[t] == e) ? 1 : 0;
    gs += gates[(size_t)t * EXPERTS + e];
    const uint64_t mask = __ballot(p);
    const int rk = __popcll(mask & ((1ull << lane) - 1ull));
    if (lane == 0) wt[w] = __popcll(mask);
    __syncthreads();
    int pre = carry;
#pragma unroll
    for (int i = 0; i < 4; ++i)
      if (i < w) pre += wt[i];
    if (p) loc1[t] = pre + rk;
    const int tot = wt[0] + wt[1] + wt[2] + wt[3];
    __syncthreads();
    if (tid == 0) carry += tot;
  }
  __syncthreads();
  if (tid == 0) counts1[e] = carry;  // pre-drop top-1 count (used for ce and loc2 base)
  // pass 2: ranks among top-2 pickers; carry continues from counts1[e]
  for (int base = 0; base < TOKENS; base += 256) {
    const int t = base + tid;
    const int p = (e2[t] == e) ? 1 : 0;
    const uint64_t mask = __ballot(p);
    const int rk = __popcll(mask & ((1ull << lane) - 1ull));
    if (lane == 0) wt[w] = __popcll(mask);
    __syncthreads();
    int pre = carry;
#pragma unroll
    for (int i = 0; i < 4; ++i)
      if (i < w) pre += wt[i];
    if (p) loc2[t] = pre + rk;
    const int tot = wt[0] + wt[1] + wt[2] + wt[3];
    __syncthreads();
    if (tid == 0) carry += tot;
  }
  // reduce gates column sum
#pragma unroll
  for (int off = 32; off > 0; off >>= 1) gs += __shfl_xor(gs, off);
  if (lane == 0) gw[w] = gs;
  __syncthreads();
  if (tid == 0) gsum[e] = gw[0] + gw[1] + gw[2] + gw[3];
}

// ---------------- K4: l_aux = sum_e S_e*C_e / 2^20 ----------------
__global__ void k_laux(const float* __restrict__ gsum, const int* __restrict__ counts1,
                       float* __restrict__ out) {
  const int lane = threadIdx.x;  // 64 threads
  float v = gsum[lane] * (float)counts1[lane];
#pragma unroll
  for (int off = 32; off > 0; off >>= 1) v += __shfl_xor(v, off);
  if (lane == 0) out[0] = v * (1.0f / 1048576.0f);
}

// ---------------- K5: sparse scatter of combine/dispatch ----------------
__global__ __launch_bounds__(256) void k_scatter(const int* __restrict__ e1,
    const int* __restrict__ e2, const float* __restrict__ g1,
    const float* __restrict__ g2, const int* __restrict__ loc1,
    const int* __restrict__ loc2, float* __restrict__ out) {
  const int t = blockIdx.x * 256 + threadIdx.x;
  const int a = e1[t], b = e2[t];
  const int l1 = loc1[t], l2 = loc2[t];
  const bool k1 = l1 < CAP;
  const bool k2 = l2 < CAP;
  const float ga = k1 ? g1[t] : 0.f;       // post-drop gates1_s
  const float gb = k2 ? g2[t] : 0.f;       // post-drop gates2_s
  const float denom = fmaxf(ga + gb, 1.1920929e-07f);  // finfo(f32).eps
  float* __restrict__ combine = out + 1;
  float* __restrict__ dispatch = out + 1 + COMB_ELEMS;
  if (k1) {
    const size_t idx = ((size_t)t * EXPERTS + a) * CAP + l1;
    combine[idx] = ga / denom;
    dispatch[idx] = 1.0f;
  }
  if (k2) {
    const size_t idx = ((size_t)t * EXPERTS + b) * CAP + l2;
    combine[idx] = gb / denom;
    dispatch[idx] = 1.0f;
  }
}

extern "C" void kernel_launch(void* const* d_in, const int* in_sizes, int n_in,
                              void* d_out, int out_size, void* d_ws, size_t ws_size,
                              hipStream_t stream) {
  const float* x = (const float*)d_in[0];
  const float* wg = (const float*)d_in[1];
  float* out = (float*)d_out;

  float* ws = (float*)d_ws;
  float* logits  = ws;                        // 524288 f32
  float* gates   = ws + 524288;               // 524288 f32
  int*   e1      = (int*)(ws + 1048576);      // 8192 i32
  int*   e2      = e1 + TOKENS;               // 8192
  int*   loc1    = e2 + TOKENS;               // 8192
  int*   loc2    = loc1 + TOKENS;             // 8192
  int*   counts1 = loc2 + TOKENS;             // 64
  float* g1      = (float*)(counts1 + 64);    // 8192 f32
  float* g2      = g1 + TOKENS;               // 8192
  float* gsum    = g2 + TOKENS;               // 64
  // total ~4.4 MB of d_ws

  // Bulk-zero entire output: combine/dispatch are >99.98% zeros.
  hipMemsetAsync(d_out, 0, (size_t)out_size * sizeof(float), stream);

  k_logits<<<TOKENS / 32, 256, 0, stream>>>(x, wg, logits);
  k_gate<<<TOKENS / 4, 256, 0, stream>>>(logits, gates, e1, e2, g1, g2);
  k_scan<<<EXPERTS, 256, 0, stream>>>(e1, e2, gates, loc1, loc2, counts1, gsum);
  k_laux<<<1, 64, 0, stream>>>(gsum, counts1, out);
  k_scatter<<<TOKENS / 256, 256, 0, stream>>>(e1, e2, g1, g2, loc1, loc2, out);
}